// Round 9
// baseline (417.856 us; speedup 1.0000x reference)
//
#include <hip/hip_runtime.h>
#include <hip/hip_bf16.h>

#define B_ 4
#define N_ 8192
#define M_ 2048
#define K_ 8

typedef __bf16 bf16x8 __attribute__((ext_vector_type(8)));
typedef __bf16 bf16x4 __attribute__((ext_vector_type(4)));
typedef float  floatx4 __attribute__((ext_vector_type(4)));

// ---------------------------------------------------------------------------
// Cast all MLP weights fp32 -> bf16 once. w1_0 [128,259] zero-padded to
// [128,288]. Flat segments: 36864 | 16384 | 32768 | 131072 = 217088 elems.
// ---------------------------------------------------------------------------
__global__ __launch_bounds__(256) void prep_weights(
    const float* __restrict__ w10, const float* __restrict__ w11,
    const float* __restrict__ w12, const float* __restrict__ w20,
    __bf16* __restrict__ w0p, __bf16* __restrict__ w11b,
    __bf16* __restrict__ w12b, __bf16* __restrict__ w20b)
{
  int t = blockIdx.x * 256 + threadIdx.x;
  if (t < 36864) {
    int o = t / 288, c = t - o * 288;
    w0p[t] = (c < 259) ? (__bf16)w10[o * 259 + c] : (__bf16)0.0f;
  } else if (t < 53248) {
    int i = t - 36864; w11b[i] = (__bf16)w11[i];
  } else if (t < 86016) {
    int i = t - 53248; w12b[i] = (__bf16)w12[i];
  } else if (t < 217088) {
    int i = t - 86016; w20b[i] = (__bf16)w20[i];
  }
}

// ---------------------------------------------------------------------------
// [B,C,L] fp32 -> [B,L,C] bf16 transpose+cast (C,L multiples of 32)
// ---------------------------------------------------------------------------
__global__ __launch_bounds__(256) void transpose_cast(
    const float* __restrict__ in, __bf16* __restrict__ out, int C, int L)
{
  __shared__ float tile[32][33];
  const int b = blockIdx.z;
  const int c0 = blockIdx.y * 32, l0 = blockIdx.x * 32;
  const int tx = threadIdx.x & 31, ty = threadIdx.x >> 5;   // ty 0..7
  const float* src = in + (size_t)b * C * L;
  #pragma unroll
  for (int i = 0; i < 4; i++)
    tile[ty + 8 * i][tx] = src[(size_t)(c0 + ty + 8 * i) * L + l0 + tx];
  __syncthreads();
  __bf16* dst = out + (size_t)b * L * C;
  #pragma unroll
  for (int i = 0; i < 4; i++)
    dst[(size_t)(l0 + ty + 8 * i) * C + c0 + tx] = (__bf16)tile[tx][ty + 8 * i];
}

// ---------------------------------------------------------------------------
// KNN v3: 32 points/block, 8 threads/point scanning disjoint 256-candidate
// chunks (streaming strict-< top-8 = stable), merge via in-wave shfl_xor
// tournament over the 8-lane group with (d,idx) lexicographic order ==
// lax.top_k tie-break (chunks index-ordered). LDS = 32 KB P only ->
// 4 blocks/CU (was 1 block/CU at 49 KB -> latency-bound ~140 us).
// Exact np formula (r1+r2)-2*dot, fp32, no FMA contraction.
// ---------------------------------------------------------------------------
__global__ __launch_bounds__(256, 4) void knn_kernel(
    const float* __restrict__ pos1, const float* __restrict__ pos2,
    int* __restrict__ idx_out)
{
  __shared__ floatx4 P[M_];        // 32 KB: (x,y,z,r) per candidate
  const int b = blockIdx.y;
  const int n0 = blockIdx.x * 32;
  const int tid = threadIdx.x;

  const float* p2 = pos2 + b * 3 * M_;
  for (int i = tid; i < M_; i += 256) {
    float x = p2[i], y = p2[M_ + i], z = p2[2 * M_ + i];
    floatx4 q;
    q[0] = x; q[1] = y; q[2] = z;
    q[3] = __fadd_rn(__fadd_rn(__fmul_rn(x, x), __fmul_rn(y, y)), __fmul_rn(z, z));
    P[i] = q;
  }
  __syncthreads();

  const int p = tid >> 3, t = tid & 7;
  const int n = n0 + p;
  const float* p1 = pos1 + b * 3 * N_;
  const float x1 = p1[n], y1 = p1[N_ + n], z1 = p1[2 * N_ + n];
  const float r1 = __fadd_rn(__fadd_rn(__fmul_rn(x1, x1), __fmul_rn(y1, y1)),
                             __fmul_rn(z1, z1));

  float bd[K_]; int bi[K_];
  #pragma unroll
  for (int j = 0; j < K_; j++) { bd[j] = 3.0e38f; bi[j] = 0; }

  const int base = t * 256;
  for (int j = 0; j < 256; j += 4) {
    float d4[4];
    #pragma unroll
    for (int jj = 0; jj < 4; jj++) {
      floatx4 q = P[base + j + jj];
      float dot = __fadd_rn(__fadd_rn(__fmul_rn(x1, q[0]), __fmul_rn(y1, q[1])),
                            __fmul_rn(z1, q[2]));
      d4[jj] = __fsub_rn(__fadd_rn(r1, q[3]), __fmul_rn(2.0f, dot));
    }
    #pragma unroll
    for (int jj = 0; jj < 4; jj++) {
      float d = d4[jj];
      if (d < bd[K_ - 1]) {          // strict <: equal-d keeps earlier index
        float cd = d; int ci = base + j + jj;
        #pragma unroll
        for (int q = 0; q < K_; q++) {
          bool lt = (cd < bd[q]);
          float nd = lt ? cd : bd[q];  int ni = lt ? ci : bi[q];
          float od = lt ? bd[q] : cd;  int oi = lt ? bi[q] : ci;
          bd[q] = nd; bi[q] = ni; cd = od; ci = oi;
        }
      }
    }
  }

  // 8-way tournament merge across the point's 8 lanes (masks 1,2,4 stay
  // within the 8-lane group). h==8 -> sentinel loses all comparisons.
  int h = 0;
  int ores[K_];
  for (int r = 0; r < K_; r++) {
    float cd = 3.3e38f; int ci = 0x7fffffff;
    #pragma unroll
    for (int q = 0; q < K_; q++) if (h == q) { cd = bd[q]; ci = bi[q]; }
    const int myi = ci;
    #pragma unroll
    for (int s = 1; s < 8; s <<= 1) {
      float od = __shfl_xor(cd, s);
      int   oi = __shfl_xor(ci, s);
      if (od < cd || (od == cd && oi < ci)) { cd = od; ci = oi; }
    }
    if (ci == myi) h++;
    ores[r] = ci;
  }
  if (t == 0) {
    int4* o = (int4*)(idx_out + ((size_t)(b * N_ + n)) * K_);
    o[0] = make_int4(ores[0], ores[1], ores[2], ores[3]);
    o[1] = make_int4(ores[4], ores[5], ores[6], ores[7]);
  }
}

// ---------------------------------------------------------------------------
// MLP1 v4: 16 points/block (128 rows), single in-place LDS buffer, fused
// register maxpool. W-major MFMA: D rows = out cols, D cols = (pt,k) rows.
// Wave tile PT=8 x WT=2 -> weights read once per block (traffic halved).
// L2+maxpool: max over K=8 = shfl_xor(1,2,4) over point-lanes, then
// scale/bias/relu on winner, direct 8B global stores (no LDS, no barrier).
// Affine+relu commute with max since s >= 0 (jax uniform).
// LDS: Y 34,816 + mrow 512 + dp 2,048 = 37.4 KB -> 4 blocks/CU.
// Fragment maps (gfx950, HW-verified): A[m=lane&15][k=quad*8+j],
// B[n=lane&15][k=quad*8+j], D[row=quad*4+reg][col=lane&15].
// ---------------------------------------------------------------------------
__global__ __launch_bounds__(256, 4) void mlp1_kernel(
    const float* __restrict__ pos1, const float* __restrict__ pos2,
    const int* __restrict__ idx, const __bf16* __restrict__ f2t,
    const __bf16* __restrict__ w0p, const float* __restrict__ s10, const float* __restrict__ b10,
    const __bf16* __restrict__ w11b, const float* __restrict__ s11, const float* __restrict__ b11,
    const __bf16* __restrict__ w12b, const float* __restrict__ s12, const float* __restrict__ b12,
    __bf16* __restrict__ maxed)
{
  __shared__ __align__(16) __bf16 Y[128 * 136];
  __shared__ int mrow[128];
  __shared__ __align__(16) float dp[128][4];

  const int b = blockIdx.y;
  const int n0 = blockIdx.x * 16;
  const int tid = threadIdx.x;
  const int wave = tid >> 6, lane = tid & 63;
  const int lrow = lane & 15, quad = lane >> 4;
  const int c0 = 32 * wave;
  const floatx4 fz = {0.f, 0.f, 0.f, 0.f};

  // prologue: neighbor index + posdiff per row (row r = point g, rank k)
  if (tid < 128) {
    const int r = tid, g = r >> 3;
    const int m = idx[(b * N_ + n0) * K_ + r];
    mrow[r] = m;
    const int n = n0 + g;
    dp[r][0] = pos2[b * 3 * M_ + m]          - pos1[b * 3 * N_ + n];
    dp[r][1] = pos2[b * 3 * M_ + M_ + m]     - pos1[b * 3 * N_ + N_ + n];
    dp[r][2] = pos2[b * 3 * M_ + 2 * M_ + m] - pos1[b * 3 * N_ + 2 * N_ + n];
    dp[r][3] = 0.f;
  }
  __syncthreads();

  int mreg[8];
  #pragma unroll
  for (int pt = 0; pt < 8; pt++) mreg[pt] = mrow[pt * 16 + lrow];

  // ---- L0: K=288 (8 ksteps from f2t global + posdiff step) -> Y cols c0..c0+31
  {
    floatx4 acc[8][2];
    #pragma unroll
    for (int pt = 0; pt < 8; pt++) { acc[pt][0] = fz; acc[pt][1] = fz; }

    #pragma unroll
    for (int ks = 0; ks < 9; ks++) {
      const int k = ks * 32 + quad * 8;
      bf16x8 wf0 = *(const bf16x8*)(w0p + (size_t)(c0 + lrow) * 288 + k);
      bf16x8 wf1 = *(const bf16x8*)(w0p + (size_t)(c0 + 16 + lrow) * 288 + k);
      #pragma unroll
      for (int pt = 0; pt < 8; pt++) {
        bf16x8 xf;
        if (ks < 8) {
          xf = *(const bf16x8*)(f2t + ((size_t)(b * M_ + mreg[pt])) * 256 + k);
        } else {
          bf16x8 v = {};
          if (quad == 0) {           // k=256..263: [dx,dy,dz,0,...]
            floatx4 d = *(const floatx4*)(&dp[pt * 16 + lrow][0]);
            v[0] = (__bf16)d[0]; v[1] = (__bf16)d[1]; v[2] = (__bf16)d[2];
          }
          xf = v;                    // quads 1-3 zero (w0p zero-padded too)
        }
        acc[pt][0] = __builtin_amdgcn_mfma_f32_16x16x32_bf16(wf0, xf, acc[pt][0], 0, 0, 0);
        acc[pt][1] = __builtin_amdgcn_mfma_f32_16x16x32_bf16(wf1, xf, acc[pt][1], 0, 0, 0);
      }
    }
    #pragma unroll
    for (int pt = 0; pt < 8; pt++) {
      #pragma unroll
      for (int wt = 0; wt < 2; wt++) {
        const int colg = c0 + wt * 16 + quad * 4;
        floatx4 s4 = *(const floatx4*)(s10 + colg);
        floatx4 b4 = *(const floatx4*)(b10 + colg);
        bf16x4 pk;
        #pragma unroll
        for (int r = 0; r < 4; r++) {
          float v = acc[pt][wt][r] * s4[r] + b4[r];
          pk[r] = (__bf16)(v > 0.f ? v : 0.f);
        }
        *(bf16x4*)(Y + (pt * 16 + lrow) * 136 + colg) = pk;
      }
    }
  }
  __syncthreads();

  // ---- L1: 128 -> 128 IN PLACE (read all, barrier, write own strip)
  {
    floatx4 acc[8][2];
    #pragma unroll
    for (int pt = 0; pt < 8; pt++) { acc[pt][0] = fz; acc[pt][1] = fz; }

    #pragma unroll
    for (int ks = 0; ks < 4; ks++) {
      const int k = ks * 32 + quad * 8;
      bf16x8 wf0 = *(const bf16x8*)(w11b + (size_t)(c0 + lrow) * 128 + k);
      bf16x8 wf1 = *(const bf16x8*)(w11b + (size_t)(c0 + 16 + lrow) * 128 + k);
      #pragma unroll
      for (int pt = 0; pt < 8; pt++) {
        bf16x8 xf = *(const bf16x8*)(Y + (pt * 16 + lrow) * 136 + k);
        acc[pt][0] = __builtin_amdgcn_mfma_f32_16x16x32_bf16(wf0, xf, acc[pt][0], 0, 0, 0);
        acc[pt][1] = __builtin_amdgcn_mfma_f32_16x16x32_bf16(wf1, xf, acc[pt][1], 0, 0, 0);
      }
    }
    __syncthreads();               // all reads of Y complete before overwrite
    #pragma unroll
    for (int pt = 0; pt < 8; pt++) {
      #pragma unroll
      for (int wt = 0; wt < 2; wt++) {
        const int colg = c0 + wt * 16 + quad * 4;
        floatx4 s4 = *(const floatx4*)(s11 + colg);
        floatx4 b4 = *(const floatx4*)(b11 + colg);
        bf16x4 pk;
        #pragma unroll
        for (int r = 0; r < 4; r++) {
          float v = acc[pt][wt][r] * s4[r] + b4[r];
          pk[r] = (__bf16)(v > 0.f ? v : 0.f);
        }
        *(bf16x4*)(Y + (pt * 16 + lrow) * 136 + colg) = pk;
      }
    }
  }
  __syncthreads();

  // ---- L2 + maxpool: two 128-col passes, Y read-only, no barriers.
  #pragma unroll
  for (int pass = 0; pass < 2; pass++) {
    const int cc0 = 128 * pass + c0;
    floatx4 acc[8][2];
    #pragma unroll
    for (int pt = 0; pt < 8; pt++) { acc[pt][0] = fz; acc[pt][1] = fz; }

    #pragma unroll
    for (int ks = 0; ks < 4; ks++) {
      const int k = ks * 32 + quad * 8;
      bf16x8 wf0 = *(const bf16x8*)(w12b + (size_t)(cc0 + lrow) * 128 + k);
      bf16x8 wf1 = *(const bf16x8*)(w12b + (size_t)(cc0 + 16 + lrow) * 128 + k);
      #pragma unroll
      for (int pt = 0; pt < 8; pt++) {
        bf16x8 xf = *(const bf16x8*)(Y + (pt * 16 + lrow) * 136 + k);
        acc[pt][0] = __builtin_amdgcn_mfma_f32_16x16x32_bf16(wf0, xf, acc[pt][0], 0, 0, 0);
        acc[pt][1] = __builtin_amdgcn_mfma_f32_16x16x32_bf16(wf1, xf, acc[pt][1], 0, 0, 0);
      }
    }

    // register maxpool over K=8 = lanes (lrow groups of 8), then affine+relu
    #pragma unroll
    for (int pt = 0; pt < 8; pt++) {
      #pragma unroll
      for (int wt = 0; wt < 2; wt++) {
        floatx4 v = acc[pt][wt];
        #pragma unroll
        for (int s = 1; s < 8; s <<= 1) {
          #pragma unroll
          for (int r = 0; r < 4; r++) {
            float o = __shfl_xor(v[r], s);
            v[r] = o > v[r] ? o : v[r];
          }
        }
        if ((lrow & 7) == 0) {
          const int colg = cc0 + wt * 16 + quad * 4;
          const int g = pt * 2 + (lrow >> 3);
          floatx4 s4 = *(const floatx4*)(s12 + colg);
          floatx4 b4 = *(const floatx4*)(b12 + colg);
          bf16x4 pk;
          #pragma unroll
          for (int r = 0; r < 4; r++) {
            float t = v[r] * s4[r] + b4[r];
            pk[r] = (__bf16)(t > 0.f ? t : 0.f);
          }
          *(bf16x4*)(maxed + ((size_t)(b * N_ + n0 + g)) * 256 + colg) = pk;
        }
      }
    }
  }
}

// ---------------------------------------------------------------------------
// MLP2: 32 rows x 128 out-cols per block, grid (1024, 2) = 2048 blocks.
// A = [maxed|f1t] bf16 contiguous, B = w20b [256][512]. Next-kstep register
// prefetch. Out fp32 floatx4.
// ---------------------------------------------------------------------------
__global__ __launch_bounds__(256, 6) void mlp2_kernel(
    const __bf16* __restrict__ maxed, const __bf16* __restrict__ f1t,
    const __bf16* __restrict__ w20b, const float* __restrict__ s20,
    const float* __restrict__ b20, float* __restrict__ out)
{
  const int rows0 = blockIdx.x * 32;           // b*N + n
  const int b = rows0 >> 13;
  const int nbase = rows0 & (N_ - 1);
  const int tid = threadIdx.x;
  const int wave = tid >> 6, lane = tid & 63;
  const int lrow = lane & 15, quad = lane >> 4;
  const int c0 = 128 * blockIdx.y + 32 * wave;
  const floatx4 fz = {0.f, 0.f, 0.f, 0.f};

  floatx4 acc[2][2];
  acc[0][0] = fz; acc[0][1] = fz; acc[1][0] = fz; acc[1][1] = fz;

  auto aptr = [&](int ks, int mt) -> const __bf16* {
    const int k = ks * 32 + quad * 8;
    return (ks < 8) ? (maxed + (size_t)(rows0 + mt * 16 + lrow) * 256 + k)
                    : (f1t + (size_t)(rows0 + mt * 16 + lrow) * 256 + (k - 256));
  };

  bf16x8 w0 = *(const bf16x8*)(w20b + (size_t)(c0 + lrow) * 512 + quad * 8);
  bf16x8 w1 = *(const bf16x8*)(w20b + (size_t)(c0 + 16 + lrow) * 512 + quad * 8);
  bf16x8 a0 = *(const bf16x8*)aptr(0, 0);
  bf16x8 a1 = *(const bf16x8*)aptr(0, 1);

  #pragma unroll
  for (int ks = 0; ks < 16; ks++) {
    bf16x8 wn0, wn1, an0, an1;
    if (ks < 15) {
      const int kn = (ks + 1) * 32 + quad * 8;
      wn0 = *(const bf16x8*)(w20b + (size_t)(c0 + lrow) * 512 + kn);
      wn1 = *(const bf16x8*)(w20b + (size_t)(c0 + 16 + lrow) * 512 + kn);
      an0 = *(const bf16x8*)aptr(ks + 1, 0);
      an1 = *(const bf16x8*)aptr(ks + 1, 1);
    }
    acc[0][0] = __builtin_amdgcn_mfma_f32_16x16x32_bf16(a0, w0, acc[0][0], 0, 0, 0);
    acc[0][1] = __builtin_amdgcn_mfma_f32_16x16x32_bf16(a0, w1, acc[0][1], 0, 0, 0);
    acc[1][0] = __builtin_amdgcn_mfma_f32_16x16x32_bf16(a1, w0, acc[1][0], 0, 0, 0);
    acc[1][1] = __builtin_amdgcn_mfma_f32_16x16x32_bf16(a1, w1, acc[1][1], 0, 0, 0);
    if (ks < 15) { w0 = wn0; w1 = wn1; a0 = an0; a1 = an1; }
  }

  #pragma unroll
  for (int ct = 0; ct < 2; ct++) {
    const int col = c0 + ct * 16 + lrow;
    const float s = s20[col];
    const float bb = b20[col];
    #pragma unroll
    for (int mt = 0; mt < 2; mt++) {
      floatx4 pk;
      #pragma unroll
      for (int r = 0; r < 4; r++) {
        float v = acc[mt][ct][r] * s + bb;
        pk[r] = v > 0.f ? v : 0.f;
      }
      const int n = nbase + mt * 16 + quad * 4;
      *(floatx4*)(out + ((size_t)(b * 256 + col)) * N_ + n) = pk;
    }
  }
}

// ---------------------------------------------------------------------------
extern "C" void kernel_launch(void* const* d_in, const int* in_sizes, int n_in,
                              void* d_out, int out_size, void* d_ws, size_t ws_size,
                              hipStream_t stream)
{
  const float* pos1     = (const float*)d_in[0];
  const float* pos2     = (const float*)d_in[1];
  const float* feature1 = (const float*)d_in[2];
  const float* feature2 = (const float*)d_in[3];
  const float* w1_0 = (const float*)d_in[4];
  const float* s1_0 = (const float*)d_in[5];
  const float* b1_0 = (const float*)d_in[6];
  const float* w1_1 = (const float*)d_in[7];
  const float* s1_1 = (const float*)d_in[8];
  const float* b1_1 = (const float*)d_in[9];
  const float* w1_2 = (const float*)d_in[10];
  const float* s1_2 = (const float*)d_in[11];
  const float* b1_2 = (const float*)d_in[12];
  const float* w2_0 = (const float*)d_in[13];
  const float* s2_0 = (const float*)d_in[14];
  const float* b2_0 = (const float*)d_in[15];

  // Workspace layout (39,231,488 B total)
  char* ws = (char*)d_ws;
  int*    idx   = (int*)(ws);                    //  1,048,576 @ 0
  __bf16* f2t   = (__bf16*)(ws + 1048576);       //  4,194,304
  __bf16* f1t   = (__bf16*)(ws + 5242880);       // 16,777,216
  __bf16* maxed = (__bf16*)(ws + 22020096);      // 16,777,216
  __bf16* w0p   = (__bf16*)(ws + 38797312);      //     73,728
  __bf16* w11b  = (__bf16*)(ws + 38871040);      //     32,768
  __bf16* w12b  = (__bf16*)(ws + 38903808);      //     65,536
  __bf16* w20b  = (__bf16*)(ws + 38969344);      //    262,144

  prep_weights<<<dim3(848), 256, 0, stream>>>(w1_0, w1_1, w1_2, w2_0,
                                              w0p, w11b, w12b, w20b);
  transpose_cast<<<dim3(M_ / 32, 8, B_), 256, 0, stream>>>(feature2, f2t, 256, M_);
  transpose_cast<<<dim3(N_ / 32, 8, B_), 256, 0, stream>>>(feature1, f1t, 256, N_);
  knn_kernel<<<dim3(N_ / 32, B_), 256, 0, stream>>>(pos1, pos2, idx);
  mlp1_kernel<<<dim3(N_ / 16, B_), 256, 0, stream>>>(
      pos1, pos2, idx, f2t, w0p, s1_0, b1_0, w11b, s1_1, b1_1, w12b, s1_2, b1_2, maxed);
  mlp2_kernel<<<dim3(1024, 2), 256, 0, stream>>>(maxed, f1t, w20b, s2_0, b2_0,
                                                 (float*)d_out);
}